// Round 11
// baseline (8907.729 us; speedup 1.0000x reference)
//
#include <hip/hip_runtime.h>

// ---------------------------------------------------------------------------
// Persistent 2-layer GRU + output Linear for MI355X (gfx950).
// B=32, T=1024, I=128, H=512, O=128.  ALL I/O FP32 (reference dtypes).
// Split-precision (hi+lo bf16) matmuls on the recurrent path (absmax 9.8e-4,
// verified R5/R6/R9). Fragment-layout rings, single-wave ballot polls,
// 4-deep rings with the full dependency set (R9, verified at 7.5 ms).
// R11: R9/R10 counters showed the step time is ring-read FABRIC BANDWIDTH:
// sc0sc1 loads bypass L2, so 64 consumer WGs each re-pulled the same ring
// slot from MALL (~13.5 MB/step uncached).  Now consumers use NORMAL cached
// loads, made coherent by ONE fence(acquire,agent) (= buffer_inv, tag-only)
// per step after the poll: first toucher per XCD fills L2, the rest hit it
// (~1.3 MB/step at MALL).  Producers keep agent-scope write-through stores
// (MALL always fresh, L2 never dirty for ring lines).  ALL dout stores are
// also write-through so buffer_inv never meets a dirty line.
// R10's register-hoist regressed (8.8 ms) and is reverted.
// Ring block layout per (kb,tile): 1024 us = [hi: 64 lanes x 8us][lo: same]
// (lane-contiguous 16B fragments; matches g_xf layout).
// Deps for step i (flags[w] = completed iterations; writer step s -> slot s&3):
//   L0: all L0 flags >= i (y0[t=i-1]), all L1 flags >= i-2 (slot free)
//   L1: all L0 flags >= i, all L1 flags >= i (y1[t=i-2]), OUT >= i-2
//   OUT: all L1 flags >= i (y1[t=i-2])
// ---------------------------------------------------------------------------

typedef __attribute__((ext_vector_type(8))) short short8;
typedef __attribute__((ext_vector_type(4))) float floatx4;

#define MFMA_BF16(a, b, c) __builtin_amdgcn_mfma_f32_16x16x32_bf16(a, b, c, 0, 0, 0)

#define NWG 130
#define EX_REC 132096            // rec-WG exchange byte offset (after weights)
#define EX_OUT 66560             // out-WG exchange byte offset (after Wout)
#define HBUF_REC (EX_REC + 24576)
#define LDS_BYTES 157696         // weights 132096 + ex 24576 + hbuf 1024
#define HID_OFF 4194304          // fp32-elem offset of hidden outputs in d_out

// g_ws bytes: flags [0,1024) | y0 ring 4x64KB | y1 ring 4x64KB
__device__ __align__(16) unsigned g_ws[131328];
#define WS_WORDS 131328
// x in fragment layout: [t][kb(4)][tile(2)][hi 64x8us | lo 64x8us]
__device__ __align__(16) unsigned short g_xf[8388608];

static __device__ __forceinline__ float bf2f(unsigned short u) {
  unsigned v = ((unsigned)u) << 16;
  return __builtin_bit_cast(float, v);
}
static __device__ __forceinline__ unsigned short f2bf(float f) {
  unsigned u = __builtin_bit_cast(unsigned, f);
  u = (u + 0x7fffu + ((u >> 16) & 1u)) >> 16;  // RNE
  return (unsigned short)u;
}
static __device__ __forceinline__ float sigf(float x) {
  return 1.f / (1.f + __expf(-x));
}
static __device__ __forceinline__ void st8(unsigned short* p, unsigned long long v) {
  __hip_atomic_store((unsigned long long*)p, v, __ATOMIC_RELAXED,
                     __HIP_MEMORY_SCOPE_AGENT);
}
static __device__ __forceinline__ void stf(float* p, float v) {
  __hip_atomic_store((unsigned*)p, __builtin_bit_cast(unsigned, v),
                     __ATOMIC_RELAXED, __HIP_MEMORY_SCOPE_AGENT);
}
static __device__ __forceinline__ void stf2(float* p, float a, float b) {
  unsigned long long w = (unsigned long long)__builtin_bit_cast(unsigned, a) |
                         ((unsigned long long)__builtin_bit_cast(unsigned, b) << 32);
  __hip_atomic_store((unsigned long long*)p, w, __ATOMIC_RELAXED,
                     __HIP_MEMORY_SCOPE_AGENT);
}
static __device__ __forceinline__ unsigned long long pack4(const unsigned short* u) {
  return (unsigned long long)u[0] | ((unsigned long long)u[1] << 16) |
         ((unsigned long long)u[2] << 32) | ((unsigned long long)u[3] << 48);
}
// NORMAL cached 16B loads (coherent after the per-step acquire fence)
static __device__ __forceinline__ void ldfrag(const unsigned short* slot, int kb,
                                              int t, int lane, short8& hi,
                                              short8& lo) {
  const unsigned short* base = slot + (kb * 2 + t) * 1024;
  hi = *(const short8*)(base + lane * 8);
  lo = *(const short8*)(base + 512 + lane * 8);
}

extern "C" __global__ void gru_init() {
  int i = blockIdx.x * blockDim.x + threadIdx.x;
  if (i < WS_WORDS) g_ws[i] = 0u;
}

extern "C" __global__ void x_arrange(const float* __restrict__ x) {
  int gid = blockIdx.x * 256 + threadIdx.x;  // 524288 total
  int t = gid >> 9;
  int rem = gid & 511;
  int kb = rem >> 7;
  int tile = (rem >> 6) & 1;
  int lane = rem & 63;
  int b = tile * 16 + (lane & 15);
  int k = kb * 32 + (lane >> 4) * 8;
  const float* src = x + b * 131072 + t * 128 + k;  // x is (B,T,I)
  short8 hi, lo;
#pragma unroll
  for (int e = 0; e < 8; ++e) {
    float v = src[e];
    unsigned short h = f2bf(v);
    hi[e] = (short)h;
    lo[e] = (short)f2bf(v - bf2f(h));
  }
  unsigned short* dst = g_xf + ((t * 4 + kb) * 2 + tile) * 1024;
  *(short8*)(dst + lane * 8) = hi;
  *(short8*)(dst + 512 + lane * 8) = lo;
}

// ---- recurrent layer step: 8 h-cols, hi/lo split MFMA ----
template <int LAYER>
__device__ __forceinline__ void layer_step(
    int i, int tid, int q, int lane, int jb,
    const unsigned short* whi, const unsigned short* wlo, float* ex, float* hbuf,
    unsigned short* y0ring, unsigned short* y1ring,
    float* __restrict__ dout,
    float bsr, float bsz, float bin, float bhn, float& hp) {
  constexpr int IHK = LAYER ? 512 : 128;
  constexpr int IHS = IHK / 32;        // ih k-blocks
  constexpr int KSW = LAYER ? 8 : 5;   // k-steps per wave
  constexpr int WSTR = IHK + 512 + 8;  // LDS weight row stride (elems)
  const int lm = lane & 15, lq = lane >> 4;

  const unsigned short* ihs =
      LAYER ? (y0ring + ((i - 1) & 3) * 32768) : (const unsigned short*)nullptr;
  const unsigned short* hhs =
      (LAYER ? y1ring : y0ring) + ((i - 1) & 3) * 32768;

  const floatx4 z4 = {0.f, 0.f, 0.f, 0.f};
  floatx4 t0h[2] = {z4, z4}, t0l[2] = {z4, z4};      // tile0 (r,z rows)
  floatx4 tih_h[2] = {z4, z4}, tih_l[2] = {z4, z4};  // tile1 n, ih part
  floatx4 thh_h[2] = {z4, z4}, thh_l[2] = {z4, z4};  // tile1 n, hh part

#pragma unroll
  for (int s = 0; s < KSW; ++s) {
    int ks = q * KSW + s;
    int colk = ks * 32 + lq * 8;
    short8 ah[2], al[2];
    if (ks < IHS) {
      if (LAYER == 0) {  // fragment-layout x, cached loads
        const unsigned short* xb = g_xf + (i * 4 + ks) * 2048;
        ah[0] = *(const short8*)(xb + lane * 8);
        al[0] = *(const short8*)(xb + 512 + lane * 8);
        ah[1] = *(const short8*)(xb + 1024 + lane * 8);
        al[1] = *(const short8*)(xb + 1536 + lane * 8);
      } else {
        ldfrag(ihs, ks, 0, lane, ah[0], al[0]);
        ldfrag(ihs, ks, 1, lane, ah[1], al[1]);
      }
    } else {
      ldfrag(hhs, ks - IHS, 0, lane, ah[0], al[0]);
      ldfrag(hhs, ks - IHS, 1, lane, ah[1], al[1]);
    }
    short8 b0h = *(const short8*)(whi + lm * WSTR + colk);
    short8 b0l = *(const short8*)(wlo + lm * WSTR + colk);
    short8 b1h = *(const short8*)(whi + (16 + lm) * WSTR + colk);
    short8 b1l = *(const short8*)(wlo + (16 + lm) * WSTR + colk);
#pragma unroll
    for (int t = 0; t < 2; ++t) {
      t0h[t] = MFMA_BF16(ah[t], b0h, t0h[t]);
      t0l[t] = MFMA_BF16(ah[t], b0l, t0l[t]);
      t0l[t] = MFMA_BF16(al[t], b0h, t0l[t]);
      if (ks < IHS) {
        tih_h[t] = MFMA_BF16(ah[t], b1h, tih_h[t]);
        tih_l[t] = MFMA_BF16(ah[t], b1l, tih_l[t]);
        tih_l[t] = MFMA_BF16(al[t], b1h, tih_l[t]);
      } else {
        thh_h[t] = MFMA_BF16(ah[t], b1h, thh_h[t]);
        thh_l[t] = MFMA_BF16(ah[t], b1l, thh_l[t]);
        thh_l[t] = MFMA_BF16(al[t], b1h, thh_l[t]);
      }
    }
  }
#pragma unroll
  for (int t = 0; t < 2; ++t) {
    *(floatx4*)(ex + ((0 * 4 + q) * 2 + t) * 256 + lane * 4) = t0h[t] + t0l[t];
    *(floatx4*)(ex + ((1 * 4 + q) * 2 + t) * 256 + lane * 4) = tih_h[t] + tih_l[t];
    *(floatx4*)(ex + ((2 * 4 + q) * 2 + t) * 256 + lane * 4) = thh_h[t] + thh_l[t];
  }
  __syncthreads();

  // elementwise: thread owns (batch m = tid>>3, col j = tid&7)
  int m = tid >> 3, j = tid & 7;
  int quad = (m >> 2) & 3, reg = m & 3, mh = m >> 4;
  int offr = (quad * 16 + j) * 4 + reg;      // r rows 0..7 in tile0
  int offz = (quad * 16 + 8 + j) * 4 + reg;  // z rows 8..15 in tile0
  float sr = 0, sz = 0, sih = 0, shh = 0;
#pragma unroll
  for (int qq = 0; qq < 4; ++qq) {
    const float* s0 = ex + ((0 * 4 + qq) * 2 + mh) * 256;
    const float* s1 = ex + ((1 * 4 + qq) * 2 + mh) * 256;
    const float* s2 = ex + ((2 * 4 + qq) * 2 + mh) * 256;
    sr += s0[offr];
    sz += s0[offz];
    sih += s1[offr];
    shh += s2[offr];
  }
  float r = sigf(sr + bsr);
  float z = sigf(sz + bsz);
  float n = tanhf(sih + bin + r * (shh + bhn));
  float h = (1.f - z) * n + z * hp;
  hp = h;
  hbuf[m * 8 + j] = h;
  if (i == (LAYER ? 1024 : 1023))  // final hidden state (write-through)
    stf(dout + HID_OFF + LAYER * 16384 + m * 512 + jb + j, h);
  __syncthreads();

  // 32 threads write this WG's 8 columns into the fragment-layout ring slot
  // (agent-scope write-through: MALL fresh, consumer L2 lines never dirty)
  if (tid < 32) {
    int mm = tid;
    int t = mm >> 4;
    int lanep = (mm & 15) + 16 * ((jb >> 3) & 3);
    int kb = jb >> 5;
    unsigned short h4[8], l4[8];
#pragma unroll
    for (int e = 0; e < 8; ++e) {
      float v = hbuf[mm * 8 + e];
      unsigned short hh = f2bf(v);
      h4[e] = hh;
      l4[e] = f2bf(v - bf2f(hh));
    }
    unsigned short* slot = (LAYER ? y1ring : y0ring) + (i & 3) * 32768;
    unsigned short* p = slot + (kb * 2 + t) * 1024 + lanep * 8;
    st8(p, pack4(h4));
    st8(p + 4, pack4(h4 + 4));
    st8(p + 512, pack4(l4));
    st8(p + 516, pack4(l4 + 4));
  }
}

__device__ __forceinline__ void out_step(
    int i, int tid, int lane, int q, int ob,
    const unsigned short* wl, float* ex,
    unsigned short* y1ring, float* __restrict__ dout, const float* bo) {
  const int lm = lane & 15, lq = lane >> 4;
  const unsigned short* slot = y1ring + ((i - 1) & 3) * 32768;  // y1[t=i-2]
  const floatx4 z4 = {0.f, 0.f, 0.f, 0.f};
  floatx4 acc[4][2];
#pragma unroll
  for (int nt = 0; nt < 4; ++nt) { acc[nt][0] = z4; acc[nt][1] = z4; }
#pragma unroll
  for (int s = 0; s < 4; ++s) {
    int ks = q * 4 + s;
    int colk = ks * 32 + lq * 8;
    short8 a0 = *(const short8*)(slot + (ks * 2 + 0) * 1024 + lane * 8);
    short8 a1 = *(const short8*)(slot + (ks * 2 + 1) * 1024 + lane * 8);
#pragma unroll
    for (int nt = 0; nt < 4; ++nt) {
      short8 b = *(const short8*)(wl + (nt * 16 + lm) * 520 + colk);
      acc[nt][0] = MFMA_BF16(a0, b, acc[nt][0]);
      acc[nt][1] = MFMA_BF16(a1, b, acc[nt][1]);
    }
  }
#pragma unroll
  for (int nt = 0; nt < 4; ++nt) {
    *(floatx4*)(ex + ((q * 4 + nt) * 2 + 0) * 256 + lane * 4) = acc[nt][0];
    *(floatx4*)(ex + ((q * 4 + nt) * 2 + 1) * 256 + lane * 4) = acc[nt][1];
  }
  __syncthreads();
  int m = tid >> 3, oc = (tid & 7) * 8;
  int t_out = i - 2;
  float sv[8];
#pragma unroll
  for (int k = 0; k < 8; ++k) {
    int o = oc + k;
    int nt = o >> 4, jj = o & 15;
    int off = (((m >> 2) & 3) * 16 + jj) * 4 + (m & 3);
    int mh = m >> 4;
    float s = bo[k];
#pragma unroll
    for (int qq = 0; qq < 4; ++qq) s += ex[((qq * 4 + nt) * 2 + mh) * 256 + off];
    sv[k] = s;
  }
  float* dst = dout + m * 131072 + t_out * 128 + ob + oc;  // (B,T,O) fp32
  stf2(dst, sv[0], sv[1]);
  stf2(dst + 2, sv[2], sv[3]);
  stf2(dst + 4, sv[4], sv[5]);
  stf2(dst + 6, sv[6], sv[7]);
}

extern "C" __global__ void __launch_bounds__(256, 1) gru_main(
    const float* __restrict__ Wih0, const float* __restrict__ Whh0,
    const float* __restrict__ bih0, const float* __restrict__ bhh0,
    const float* __restrict__ Wih1, const float* __restrict__ Whh1,
    const float* __restrict__ bih1, const float* __restrict__ bhh1,
    const float* __restrict__ Wout, const float* __restrict__ boutp,
    float* __restrict__ dout) {
  extern __shared__ char smem[];
  __shared__ int sbail;

  int* flags = (int*)g_ws;
  unsigned short* y0ring = (unsigned short*)((char*)g_ws + 1024);
  unsigned short* y1ring = (unsigned short*)((char*)g_ws + 1024 + 262144);

  const int w = blockIdx.x;
  const int tid = threadIdx.x;
  const int lane = tid & 63;
  const int q = tid >> 6;
  const int role = (w < 128) ? ((w < 64) ? 0 : 1) : 2;

  if (tid == 0) sbail = 0;

  unsigned short* whi = (unsigned short*)smem;
  float* ex = (float*)(smem + (role == 2 ? EX_OUT : EX_REC));
  float* hbuf = (float*)(smem + HBUF_REC);
  {
    int exn = (role == 2) ? 8192 : 6144;
    for (int idx = tid; idx < exn; idx += 256) ex[idx] = 0.f;
  }

  float bsr = 0, bsz = 0, bin = 0, bhn = 0;
  float bo[8] = {0, 0, 0, 0, 0, 0, 0, 0};
  int jb = 0, ob = 0;
  const unsigned short* wlo = nullptr;

  if (role < 2) {
    jb = (role == 0 ? w : w - 64) * 8;
    const int IHK = role ? 512 : 128;
    const int KTOT = IHK + 512;
    const int WSTR = KTOT + 8;
    unsigned short* wlo_w = whi + 32 * WSTR;
    wlo = wlo_w;
    const float* Wih = role ? Wih1 : Wih0;
    const float* Whh = role ? Whh1 : Whh0;
    const float* bih = role ? bih1 : bih0;
    const float* bhh = role ? bhh1 : bhh0;
    int cpr = KTOT / 8;
    for (int idx = tid; idx < 32 * cpr; idx += 256) {
      int r = idx / cpr, c = idx - r * cpr;
      int k0 = c * 8;
      short8 hi8 = {0, 0, 0, 0, 0, 0, 0, 0}, lo8 = {0, 0, 0, 0, 0, 0, 0, 0};
      if (r < 24) {  // rows 24..31 zero pad
        int gate = r >> 3, jl = r & 7;
        int grow = gate * 512 + jb + jl;
        const float* src = (k0 < IHK) ? (Wih + grow * IHK + k0)
                                      : (Whh + grow * 512 + (k0 - IHK));
#pragma unroll
        for (int e = 0; e < 8; ++e) {
          float v = src[e];
          unsigned short h16 = f2bf(v);
          hi8[e] = (short)h16;
          lo8[e] = (short)f2bf(v - bf2f(h16));
        }
      }
      *(short8*)(whi + r * WSTR + k0) = hi8;
      *(short8*)(wlo_w + r * WSTR + k0) = lo8;
    }
    for (int idx = tid; idx < 32 * 8; idx += 256) {
      int r = idx >> 3, kk = KTOT + (idx & 7);
      whi[r * WSTR + kk] = 0;
      wlo_w[r * WSTR + kk] = 0;
    }
    int g0 = jb + (tid & 7);
    bsr = bih[g0] + bhh[g0];
    bsz = bih[512 + g0] + bhh[512 + g0];
    bin = bih[1024 + g0];
    bhn = bhh[1024 + g0];
  } else {
    ob = (w - 128) * 64;
    for (int idx = tid; idx < 64 * 64; idx += 256) {
      int r = idx >> 6, c = idx & 63;
      const float* src = Wout + (ob + r) * 512 + c * 8;
      short8 hi8;
#pragma unroll
      for (int e = 0; e < 8; ++e) hi8[e] = (short)f2bf(src[e]);
      *(short8*)(whi + r * 520 + c * 8) = hi8;
    }
    for (int idx = tid; idx < 64 * 8; idx += 256)
      whi[(idx >> 3) * 520 + 512 + (idx & 7)] = 0;
#pragma unroll
    for (int k = 0; k < 8; ++k) bo[k] = boutp[ob + (tid & 7) * 8 + k];
  }
  __syncthreads();

  float hp = 0.f;

  for (int i = 0; i < 1026; ++i) {
    // ---- single-wave ballot poll (full dependency set — see header) ----
    if (i > 0 && tid < 64) {
      int guard = 0;
      for (;;) {
        bool ok;
        if (role == 0) {
          ok = (__hip_atomic_load(flags + tid, __ATOMIC_RELAXED,
                                  __HIP_MEMORY_SCOPE_AGENT) >= i) &&
               (__hip_atomic_load(flags + 64 + tid, __ATOMIC_RELAXED,
                                  __HIP_MEMORY_SCOPE_AGENT) >= i - 2);
        } else if (role == 1) {
          ok = (__hip_atomic_load(flags + tid, __ATOMIC_RELAXED,
                                  __HIP_MEMORY_SCOPE_AGENT) >= i) &&
               (__hip_atomic_load(flags + 64 + tid, __ATOMIC_RELAXED,
                                  __HIP_MEMORY_SCOPE_AGENT) >= i);
          if (tid < 2)
            ok = ok && (__hip_atomic_load(flags + 128 + tid, __ATOMIC_RELAXED,
                                          __HIP_MEMORY_SCOPE_AGENT) >= i - 2);
        } else {
          ok = __hip_atomic_load(flags + 64 + tid, __ATOMIC_RELAXED,
                                 __HIP_MEMORY_SCOPE_AGENT) >= i;
        }
        if (__ballot(ok) == ~0ull) break;
        __builtin_amdgcn_s_sleep(1);
        if (++guard > (1 << 17)) { sbail = 1; break; }
      }
    }
    // every wave invalidates L1/L2 (tag-only) so the normal cached ring
    // loads below observe the producers' write-through data
    __builtin_amdgcn_fence(__ATOMIC_ACQUIRE, "agent");
    __syncthreads();
    if (sbail) break;

    bool active = (role == 0) ? (i < 1024)
                : (role == 1) ? (i >= 1 && i < 1025)
                              : (i >= 2);
    if (active) {
      if (role == 0) {
        layer_step<0>(i, tid, q, lane, jb, whi, wlo, ex, hbuf, y0ring, y1ring,
                      dout, bsr, bsz, bin, bhn, hp);
      } else if (role == 1) {
        layer_step<1>(i, tid, q, lane, jb, whi, wlo, ex, hbuf, y0ring, y1ring,
                      dout, bsr, bsz, bin, bhn, hp);
      } else {
        out_step(i, tid, lane, q, ob, whi, ex, y1ring, dout, bo);
      }
    }
    // ---- publish: barrier drains vmcnt (ring stores at MALL), then flag ----
    __syncthreads();
    if (tid == 0)
      __hip_atomic_store(&flags[w], i + 1, __ATOMIC_RELAXED,
                         __HIP_MEMORY_SCOPE_AGENT);
  }
}

extern "C" void kernel_launch(void* const* d_in, const int* in_sizes, int n_in,
                              void* d_out, int out_size, void* d_ws, size_t ws_size,
                              hipStream_t stream) {
  const float* x = (const float*)d_in[0];
  const float* Wih0 = (const float*)d_in[1];
  const float* Whh0 = (const float*)d_in[2];
  const float* bih0 = (const float*)d_in[3];
  const float* bhh0 = (const float*)d_in[4];
  const float* Wih1 = (const float*)d_in[5];
  const float* Whh1 = (const float*)d_in[6];
  const float* bih1 = (const float*)d_in[7];
  const float* bhh1 = (const float*)d_in[8];
  const float* Wout = (const float*)d_in[9];
  const float* bout = (const float*)d_in[10];

  hipLaunchKernelGGL(gru_init, dim3((WS_WORDS + 255) / 256), dim3(256), 0,
                     stream);
  hipLaunchKernelGGL(x_arrange, dim3(524288 / 256), dim3(256), 0, stream, x);

  hipFuncSetAttribute((const void*)gru_main,
                      hipFuncAttributeMaxDynamicSharedMemorySize, LDS_BYTES);
  hipLaunchKernelGGL(gru_main, dim3(NWG), dim3(256), LDS_BYTES, stream,
                     Wih0, Whh0, bih0, bhh0, Wih1, Whh1, bih1, bhh1, Wout,
                     bout, (float*)d_out);
}

// Round 12
// 7177.737 us; speedup vs baseline: 1.2410x; 1.2410x over previous
//
#include <hip/hip_runtime.h>

// ---------------------------------------------------------------------------
// Persistent 2-layer GRU + output Linear for MI355X (gfx950).
// B=32, T=1024, I=128, H=512, O=128.  ALL I/O FP32 (reference dtypes).
// Split-precision (hi+lo bf16) matmuls on the recurrent path (absmax 9.8e-4,
// verified R5/R6/R9). Fragment-layout rings, single-wave ballot polls.
// R12: R9/R10/R11 all ran ~7.5-8.9 ms with identical FETCH -> step time is
// ring-read FABRIC VOLUME (~12.3 MB/step, 64x-redundant across consumer WGs;
// sc loads bypass L2, and R11's per-step buffer_inv nuked L2 reuse anyway).
// Fix: FULL-SEQUENCE rings (one 64KB slot per timestep, written once) ->
// consumer PLAIN CACHED loads are always coherent (address never rewritten;
// one tag-invalidate at kernel entry clears prior-launch lines; producers
// write through to MALL at agent scope; flag stored only after vmcnt drain).
// First toucher per XCD fills L2, 15 other WGs hit L2: ~1.2 MB/step fabric.
// No slot reuse -> no anti-deps: L0 waits L0 peers >= i; L1 waits L0,L1 >= i;
// OUT waits L1 >= i.  dout stores back to plain (write-back).
// Slot map: y0[idx] holds h0[t=idx-1] (idx0 = zeros); L0 step i reads y0[i],
// writes y0[i+1].  y1[idx] holds h1[t=idx-1]; L1 step i reads y0[i] (ih),
// y1[i-1] (hh), writes y1[i].  OUT step i reads y1[i-1] (t=i-2).
// ---------------------------------------------------------------------------

typedef __attribute__((ext_vector_type(8))) short short8;
typedef __attribute__((ext_vector_type(4))) float floatx4;

#define MFMA_BF16(a, b, c) __builtin_amdgcn_mfma_f32_16x16x32_bf16(a, b, c, 0, 0, 0)

#define NWG 130
#define EX_REC 132096            // rec-WG exchange byte offset (after weights)
#define EX_OUT 66560             // out-WG exchange byte offset (after Wout)
#define HBUF_REC (EX_REC + 24576)
#define LDS_BYTES 157696         // weights 132096 + ex 24576 + hbuf 1024
#define HID_OFF 4194304          // fp32-elem offset of hidden outputs in d_out
#define SLOT 32768               // ushorts per ring slot (hi 16K + lo 16K)

__device__ __align__(16) unsigned g_flags[256];
// full-sequence rings: 1025 slots x 32768 ushorts = 67 MB each
__device__ __align__(16) unsigned short g_y0[33587200];
__device__ __align__(16) unsigned short g_y1[33587200];
// x in fragment layout: [t][kb(4)][tile(2)][hi 64x8us | lo 64x8us]
__device__ __align__(16) unsigned short g_xf[8388608];

static __device__ __forceinline__ float bf2f(unsigned short u) {
  unsigned v = ((unsigned)u) << 16;
  return __builtin_bit_cast(float, v);
}
static __device__ __forceinline__ unsigned short f2bf(float f) {
  unsigned u = __builtin_bit_cast(unsigned, f);
  u = (u + 0x7fffu + ((u >> 16) & 1u)) >> 16;  // RNE
  return (unsigned short)u;
}
static __device__ __forceinline__ float sigf(float x) {
  return 1.f / (1.f + __expf(-x));
}
static __device__ __forceinline__ void st8(unsigned short* p, unsigned long long v) {
  __hip_atomic_store((unsigned long long*)p, v, __ATOMIC_RELAXED,
                     __HIP_MEMORY_SCOPE_AGENT);
}
static __device__ __forceinline__ unsigned long long pack4(const unsigned short* u) {
  return (unsigned long long)u[0] | ((unsigned long long)u[1] << 16) |
         ((unsigned long long)u[2] << 32) | ((unsigned long long)u[3] << 48);
}
// plain cached 16B fragment loads — slot addresses are write-once, so L2
// copies are always fresh (see header)
static __device__ __forceinline__ void ldfrag(const unsigned short* slot, int kb,
                                              int t, int lane, short8& hi,
                                              short8& lo) {
  const unsigned short* base = slot + (kb * 2 + t) * 1024 + lane * 8;
  hi = *(const short8*)base;
  lo = *(const short8*)(base + 512);
}

extern "C" __global__ void gru_init() {
  int i = blockIdx.x * blockDim.x + threadIdx.x;  // 33024 threads
  if (i < 256) {
    g_flags[i] = 0u;
  } else if (i < 16640) {
    ((unsigned*)g_y0)[i - 256] = 0u;   // y0 slot 0 = zeros (h0[-1])
  } else if (i < 33024) {
    ((unsigned*)g_y1)[i - 16640] = 0u; // y1 slot 0 = zeros (h1[-1])
  }
}

extern "C" __global__ void x_arrange(const float* __restrict__ x) {
  int gid = blockIdx.x * 256 + threadIdx.x;  // 524288 total
  int t = gid >> 9;
  int rem = gid & 511;
  int kb = rem >> 7;
  int tile = (rem >> 6) & 1;
  int lane = rem & 63;
  int b = tile * 16 + (lane & 15);
  int k = kb * 32 + (lane >> 4) * 8;
  const float* src = x + b * 131072 + t * 128 + k;  // x is (B,T,I)
  short8 hi, lo;
#pragma unroll
  for (int e = 0; e < 8; ++e) {
    float v = src[e];
    unsigned short h = f2bf(v);
    hi[e] = (short)h;
    lo[e] = (short)f2bf(v - bf2f(h));
  }
  unsigned short* dst = g_xf + ((t * 4 + kb) * 2 + tile) * 1024;
  *(short8*)(dst + lane * 8) = hi;
  *(short8*)(dst + 512 + lane * 8) = lo;
}

// ---- recurrent layer step: 8 h-cols, hi/lo split MFMA ----
template <int LAYER>
__device__ __forceinline__ void layer_step(
    int i, int tid, int q, int lane, int jb,
    const unsigned short* whi, const unsigned short* wlo, float* ex, float* hbuf,
    float* __restrict__ dout,
    float bsr, float bsz, float bin, float bhn, float& hp) {
  constexpr int IHK = LAYER ? 512 : 128;
  constexpr int IHS = IHK / 32;        // ih k-blocks
  constexpr int KSW = LAYER ? 8 : 5;   // k-steps per wave
  constexpr int WSTR = IHK + 512 + 8;  // LDS weight row stride (elems)
  const int lm = lane & 15, lq = lane >> 4;

  const unsigned short* ihs = LAYER ? (g_y0 + (size_t)i * SLOT) : nullptr;
  const unsigned short* hhs =
      LAYER ? (g_y1 + (size_t)(i - 1) * SLOT) : (g_y0 + (size_t)i * SLOT);

  const floatx4 z4 = {0.f, 0.f, 0.f, 0.f};
  floatx4 t0h[2] = {z4, z4}, t0l[2] = {z4, z4};      // tile0 (r,z rows)
  floatx4 tih_h[2] = {z4, z4}, tih_l[2] = {z4, z4};  // tile1 n, ih part
  floatx4 thh_h[2] = {z4, z4}, thh_l[2] = {z4, z4};  // tile1 n, hh part

#pragma unroll
  for (int s = 0; s < KSW; ++s) {
    int ks = q * KSW + s;
    int colk = ks * 32 + lq * 8;
    short8 ah[2], al[2];
    if (ks < IHS) {
      if (LAYER == 0) {  // fragment-layout x, cached loads
        const unsigned short* xb = g_xf + (i * 4 + ks) * 2048;
        ah[0] = *(const short8*)(xb + lane * 8);
        al[0] = *(const short8*)(xb + 512 + lane * 8);
        ah[1] = *(const short8*)(xb + 1024 + lane * 8);
        al[1] = *(const short8*)(xb + 1536 + lane * 8);
      } else {
        ldfrag(ihs, ks, 0, lane, ah[0], al[0]);
        ldfrag(ihs, ks, 1, lane, ah[1], al[1]);
      }
    } else {
      ldfrag(hhs, ks - IHS, 0, lane, ah[0], al[0]);
      ldfrag(hhs, ks - IHS, 1, lane, ah[1], al[1]);
    }
    short8 b0h = *(const short8*)(whi + lm * WSTR + colk);
    short8 b0l = *(const short8*)(wlo + lm * WSTR + colk);
    short8 b1h = *(const short8*)(whi + (16 + lm) * WSTR + colk);
    short8 b1l = *(const short8*)(wlo + (16 + lm) * WSTR + colk);
#pragma unroll
    for (int t = 0; t < 2; ++t) {
      t0h[t] = MFMA_BF16(ah[t], b0h, t0h[t]);
      t0l[t] = MFMA_BF16(ah[t], b0l, t0l[t]);
      t0l[t] = MFMA_BF16(al[t], b0h, t0l[t]);
      if (ks < IHS) {
        tih_h[t] = MFMA_BF16(ah[t], b1h, tih_h[t]);
        tih_l[t] = MFMA_BF16(ah[t], b1l, tih_l[t]);
        tih_l[t] = MFMA_BF16(al[t], b1h, tih_l[t]);
      } else {
        thh_h[t] = MFMA_BF16(ah[t], b1h, thh_h[t]);
        thh_l[t] = MFMA_BF16(ah[t], b1l, thh_l[t]);
        thh_l[t] = MFMA_BF16(al[t], b1h, thh_l[t]);
      }
    }
  }
#pragma unroll
  for (int t = 0; t < 2; ++t) {
    *(floatx4*)(ex + ((0 * 4 + q) * 2 + t) * 256 + lane * 4) = t0h[t] + t0l[t];
    *(floatx4*)(ex + ((1 * 4 + q) * 2 + t) * 256 + lane * 4) = tih_h[t] + tih_l[t];
    *(floatx4*)(ex + ((2 * 4 + q) * 2 + t) * 256 + lane * 4) = thh_h[t] + thh_l[t];
  }
  __syncthreads();

  // elementwise: thread owns (batch m = tid>>3, col j = tid&7)
  int m = tid >> 3, j = tid & 7;
  int quad = (m >> 2) & 3, reg = m & 3, mh = m >> 4;
  int offr = (quad * 16 + j) * 4 + reg;      // r rows 0..7 in tile0
  int offz = (quad * 16 + 8 + j) * 4 + reg;  // z rows 8..15 in tile0
  float sr = 0, sz = 0, sih = 0, shh = 0;
#pragma unroll
  for (int qq = 0; qq < 4; ++qq) {
    const float* s0 = ex + ((0 * 4 + qq) * 2 + mh) * 256;
    const float* s1 = ex + ((1 * 4 + qq) * 2 + mh) * 256;
    const float* s2 = ex + ((2 * 4 + qq) * 2 + mh) * 256;
    sr += s0[offr];
    sz += s0[offz];
    sih += s1[offr];
    shh += s2[offr];
  }
  float r = sigf(sr + bsr);
  float z = sigf(sz + bsz);
  float n = tanhf(sih + bin + r * (shh + bhn));
  float h = (1.f - z) * n + z * hp;
  hp = h;
  hbuf[m * 8 + j] = h;
  if (i == (LAYER ? 1024 : 1023))  // final hidden state (plain store)
    dout[HID_OFF + LAYER * 16384 + m * 512 + jb + j] = h;
  __syncthreads();

  // 32 threads write this WG's 8 columns into the write-once ring slot
  // (agent-scope write-through: lands at MALL; consumers L2-fill from there)
  if (tid < 32) {
    int mm = tid;
    int t = mm >> 4;
    int lanep = (mm & 15) + 16 * ((jb >> 3) & 3);
    int kb = jb >> 5;
    unsigned short h4[8], l4[8];
#pragma unroll
    for (int e = 0; e < 8; ++e) {
      float v = hbuf[mm * 8 + e];
      unsigned short hh = f2bf(v);
      h4[e] = hh;
      l4[e] = f2bf(v - bf2f(hh));
    }
    unsigned short* slot =
        LAYER ? (g_y1 + (size_t)i * SLOT) : (g_y0 + (size_t)(i + 1) * SLOT);
    unsigned short* p = slot + (kb * 2 + t) * 1024 + lanep * 8;
    st8(p, pack4(h4));
    st8(p + 4, pack4(h4 + 4));
    st8(p + 512, pack4(l4));
    st8(p + 516, pack4(l4 + 4));
  }
}

__device__ __forceinline__ void out_step(
    int i, int tid, int lane, int q, int ob,
    const unsigned short* wl, float* ex,
    float* __restrict__ dout, const float* bo) {
  const int lm = lane & 15, lq = lane >> 4;
  const unsigned short* slot = g_y1 + (size_t)(i - 1) * SLOT;  // y1[t=i-2]
  const floatx4 z4 = {0.f, 0.f, 0.f, 0.f};
  floatx4 acc[4][2];
#pragma unroll
  for (int nt = 0; nt < 4; ++nt) { acc[nt][0] = z4; acc[nt][1] = z4; }
#pragma unroll
  for (int s = 0; s < 4; ++s) {
    int ks = q * 4 + s;
    int colk = ks * 32 + lq * 8;
    short8 a0 = *(const short8*)(slot + (ks * 2 + 0) * 1024 + lane * 8);
    short8 a1 = *(const short8*)(slot + (ks * 2 + 1) * 1024 + lane * 8);
#pragma unroll
    for (int nt = 0; nt < 4; ++nt) {
      short8 b = *(const short8*)(wl + (nt * 16 + lm) * 520 + colk);
      acc[nt][0] = MFMA_BF16(a0, b, acc[nt][0]);
      acc[nt][1] = MFMA_BF16(a1, b, acc[nt][1]);
    }
  }
#pragma unroll
  for (int nt = 0; nt < 4; ++nt) {
    *(floatx4*)(ex + ((q * 4 + nt) * 2 + 0) * 256 + lane * 4) = acc[nt][0];
    *(floatx4*)(ex + ((q * 4 + nt) * 2 + 1) * 256 + lane * 4) = acc[nt][1];
  }
  __syncthreads();
  int m = tid >> 3, oc = (tid & 7) * 8;
  int t_out = i - 2;
  float sv[8];
#pragma unroll
  for (int k = 0; k < 8; ++k) {
    int o = oc + k;
    int nt = o >> 4, jj = o & 15;
    int off = (((m >> 2) & 3) * 16 + jj) * 4 + (m & 3);
    int mh = m >> 4;
    float s = bo[k];
#pragma unroll
    for (int qq = 0; qq < 4; ++qq) s += ex[((qq * 4 + nt) * 2 + mh) * 256 + off];
    sv[k] = s;
  }
  float* dst = dout + m * 131072 + t_out * 128 + ob + oc;  // (B,T,O) fp32
  *(floatx4*)dst = floatx4{sv[0], sv[1], sv[2], sv[3]};
  *(floatx4*)(dst + 4) = floatx4{sv[4], sv[5], sv[6], sv[7]};
}

extern "C" __global__ void __launch_bounds__(256, 1) gru_main(
    const float* __restrict__ Wih0, const float* __restrict__ Whh0,
    const float* __restrict__ bih0, const float* __restrict__ bhh0,
    const float* __restrict__ Wih1, const float* __restrict__ Whh1,
    const float* __restrict__ bih1, const float* __restrict__ bhh1,
    const float* __restrict__ Wout, const float* __restrict__ boutp,
    float* __restrict__ dout) {
  extern __shared__ char smem[];
  __shared__ int sbail;

  int* flags = (int*)g_flags;

  const int w = blockIdx.x;
  const int tid = threadIdx.x;
  const int lane = tid & 63;
  const int q = tid >> 6;
  const int role = (w < 128) ? ((w < 64) ? 0 : 1) : 2;

  if (tid == 0) sbail = 0;

  unsigned short* whi = (unsigned short*)smem;
  float* ex = (float*)(smem + (role == 2 ? EX_OUT : EX_REC));
  float* hbuf = (float*)(smem + HBUF_REC);
  {
    int exn = (role == 2) ? 8192 : 6144;
    for (int idx = tid; idx < exn; idx += 256) ex[idx] = 0.f;
  }

  float bsr = 0, bsz = 0, bin = 0, bhn = 0;
  float bo[8] = {0, 0, 0, 0, 0, 0, 0, 0};
  int jb = 0, ob = 0;
  const unsigned short* wlo = nullptr;

  if (role < 2) {
    jb = (role == 0 ? w : w - 64) * 8;
    const int IHK = role ? 512 : 128;
    const int KTOT = IHK + 512;
    const int WSTR = KTOT + 8;
    unsigned short* wlo_w = whi + 32 * WSTR;
    wlo = wlo_w;
    const float* Wih = role ? Wih1 : Wih0;
    const float* Whh = role ? Whh1 : Whh0;
    const float* bih = role ? bih1 : bih0;
    const float* bhh = role ? bhh1 : bhh0;
    int cpr = KTOT / 8;
    for (int idx = tid; idx < 32 * cpr; idx += 256) {
      int r = idx / cpr, c = idx - r * cpr;
      int k0 = c * 8;
      short8 hi8 = {0, 0, 0, 0, 0, 0, 0, 0}, lo8 = {0, 0, 0, 0, 0, 0, 0, 0};
      if (r < 24) {  // rows 24..31 zero pad
        int gate = r >> 3, jl = r & 7;
        int grow = gate * 512 + jb + jl;
        const float* src = (k0 < IHK) ? (Wih + grow * IHK + k0)
                                      : (Whh + grow * 512 + (k0 - IHK));
#pragma unroll
        for (int e = 0; e < 8; ++e) {
          float v = src[e];
          unsigned short h16 = f2bf(v);
          hi8[e] = (short)h16;
          lo8[e] = (short)f2bf(v - bf2f(h16));
        }
      }
      *(short8*)(whi + r * WSTR + k0) = hi8;
      *(short8*)(wlo_w + r * WSTR + k0) = lo8;
    }
    for (int idx = tid; idx < 32 * 8; idx += 256) {
      int r = idx >> 3, kk = KTOT + (idx & 7);
      whi[r * WSTR + kk] = 0;
      wlo_w[r * WSTR + kk] = 0;
    }
    int g0 = jb + (tid & 7);
    bsr = bih[g0] + bhh[g0];
    bsz = bih[512 + g0] + bhh[512 + g0];
    bin = bih[1024 + g0];
    bhn = bhh[1024 + g0];
  } else {
    ob = (w - 128) * 64;
    for (int idx = tid; idx < 64 * 64; idx += 256) {
      int r = idx >> 6, c = idx & 63;
      const float* src = Wout + (ob + r) * 512 + c * 8;
      short8 hi8;
#pragma unroll
      for (int e = 0; e < 8; ++e) hi8[e] = (short)f2bf(src[e]);
      *(short8*)(whi + r * 520 + c * 8) = hi8;
    }
    for (int idx = tid; idx < 64 * 8; idx += 256)
      whi[(idx >> 3) * 520 + 512 + (idx & 7)] = 0;
#pragma unroll
    for (int k = 0; k < 8; ++k) bo[k] = boutp[ob + (tid & 7) * 8 + k];
  }
  // one-time tag invalidate: clears any prior-launch ring lines from L1/L2
  __builtin_amdgcn_fence(__ATOMIC_ACQUIRE, "agent");
  __syncthreads();

  float hp = 0.f;

  for (int i = 0; i < 1026; ++i) {
    // ---- single-wave ballot poll (true deps only; no anti-deps) ----
    if (i > 0 && tid < 64) {
      int guard = 0;
      for (;;) {
        bool ok;
        if (role == 0) {         // all L0 peers finished step i-1
          ok = __hip_atomic_load(flags + tid, __ATOMIC_RELAXED,
                                 __HIP_MEMORY_SCOPE_AGENT) >= i;
        } else if (role == 1) {  // all L0 and L1 peers finished step i-1
          ok = (__hip_atomic_load(flags + tid, __ATOMIC_RELAXED,
                                  __HIP_MEMORY_SCOPE_AGENT) >= i) &&
               (__hip_atomic_load(flags + 64 + tid, __ATOMIC_RELAXED,
                                  __HIP_MEMORY_SCOPE_AGENT) >= i);
        } else {                 // OUT: all L1 finished step i-1
          ok = __hip_atomic_load(flags + 64 + tid, __ATOMIC_RELAXED,
                                 __HIP_MEMORY_SCOPE_AGENT) >= i;
        }
        if (__ballot(ok) == ~0ull) break;
        __builtin_amdgcn_s_sleep(1);
        if (++guard > (1 << 17)) { sbail = 1; break; }
      }
    }
    __syncthreads();
    if (sbail) break;

    bool active = (role == 0) ? (i < 1024)
                : (role == 1) ? (i >= 1 && i < 1025)
                              : (i >= 2);
    if (active) {
      if (role == 0) {
        layer_step<0>(i, tid, q, lane, jb, whi, wlo, ex, hbuf, dout,
                      bsr, bsz, bin, bhn, hp);
      } else if (role == 1) {
        layer_step<1>(i, tid, q, lane, jb, whi, wlo, ex, hbuf, dout,
                      bsr, bsz, bin, bhn, hp);
      } else {
        out_step(i, tid, lane, q, ob, whi, ex, dout, bo);
      }
    }
    // ---- publish: barrier drains vmcnt (ring stores at MALL), then flag ----
    __syncthreads();
    if (tid == 0)
      __hip_atomic_store(&flags[w], i + 1, __ATOMIC_RELAXED,
                         __HIP_MEMORY_SCOPE_AGENT);
  }
}

extern "C" void kernel_launch(void* const* d_in, const int* in_sizes, int n_in,
                              void* d_out, int out_size, void* d_ws, size_t ws_size,
                              hipStream_t stream) {
  const float* x = (const float*)d_in[0];
  const float* Wih0 = (const float*)d_in[1];
  const float* Whh0 = (const float*)d_in[2];
  const float* bih0 = (const float*)d_in[3];
  const float* bhh0 = (const float*)d_in[4];
  const float* Wih1 = (const float*)d_in[5];
  const float* Whh1 = (const float*)d_in[6];
  const float* bih1 = (const float*)d_in[7];
  const float* bhh1 = (const float*)d_in[8];
  const float* Wout = (const float*)d_in[9];
  const float* bout = (const float*)d_in[10];

  hipLaunchKernelGGL(gru_init, dim3(129), dim3(256), 0, stream);
  hipLaunchKernelGGL(x_arrange, dim3(524288 / 256), dim3(256), 0, stream, x);

  hipFuncSetAttribute((const void*)gru_main,
                      hipFuncAttributeMaxDynamicSharedMemorySize, LDS_BYTES);
  hipLaunchKernelGGL(gru_main, dim3(NWG), dim3(256), LDS_BYTES, stream,
                     Wih0, Whh0, bih0, bhh0, Wih1, Whh1, bih1, bhh1, Wout,
                     bout, (float*)d_out);
}